// Round 5
// baseline (1136.504 us; speedup 1.0000x reference)
//
#include <hip/hip_runtime.h>
#include <hip/hip_bf16.h>
#include <stdint.h>

// SlotAttention MI355X. Round 5: gemm_kv256 rescheduled — barrier-free phases,
// 2-slot double buffer, one junction (2 barriers + vmcnt(8)) per 128-MFMA K-tile.
// Rest identical to round 4. B=32 L=2048 D=1024 N=16 ITERS=4 H=2048.

typedef __bf16 bf16;
typedef __bf16 bf16x2 __attribute__((ext_vector_type(2)));
typedef __bf16 bf16x4 __attribute__((ext_vector_type(4)));
typedef __bf16 bf16x8 __attribute__((ext_vector_type(8)));
typedef float  f32x4  __attribute__((ext_vector_type(4)));

#define MFMA16(a,b,c) __builtin_amdgcn_mfma_f32_16x16x32_bf16((a),(b),(c),0,0,0)

__device__ __forceinline__ void gload16(const void* g, void* l) {
  __builtin_amdgcn_global_load_lds((__attribute__((address_space(1))) const void*)g,
                                   (__attribute__((address_space(3))) void*)l, 16, 0, 0);
}
#define GL16(src, dst) gload16((const void*)(src), (void*)(dst))

// ---- fused K/V projection, 256x256 tile, BK=64, junction-pipelined ----
// C[M,2048] = A[M,1024] @ Wkv[2048,1024]^T ; cols<1024 -> kout else vout.
// 512 thr = 8 waves (2M x 4N); per-wave C = 128x64 = 8 Mf x 4 Nf.
// LDS: 2 slots x (A 32KB + B 32KB). Fragment-major: frag g=(rowfrag*2+kk) at
// g*1024 + lane*16 (conflict-free b128, linear gload_lds dest).
// Phase p=(kk,mh): 4(+4 B at kk-change) ds_read_b128 -> lgkm0 -> 16 MFMA. No barriers.
// Junction per tile: barrier; stage t+2; vmcnt(8); barrier.
#define KV_PHASE(SB, KKC, MH, LOADB)                                              \
  {                                                                               \
    if (LOADB) {                                                                  \
      _Pragma("unroll")                                                           \
      for (int nf = 0; nf < 4; ++nf)                                              \
        bv[nf] = *(const bf16x8*)((SB) + 32768 + (wn * 8 + nf * 2 + (KKC)) * 1024 + l * 16); \
    }                                                                             \
    bf16x8 av_[4];                                                                \
    _Pragma("unroll")                                                             \
    for (int m = 0; m < 4; ++m)                                                   \
      av_[m] = *(const bf16x8*)((SB) + (wm * 16 + ((MH) * 4 + m) * 2 + (KKC)) * 1024 + l * 16); \
    asm volatile("s_waitcnt lgkmcnt(0)" ::: "memory");                            \
    __builtin_amdgcn_sched_barrier(0);                                            \
    __builtin_amdgcn_s_setprio(1);                                                \
    _Pragma("unroll")                                                             \
    for (int m = 0; m < 4; ++m)                                                   \
      _Pragma("unroll")                                                           \
      for (int nf = 0; nf < 4; ++nf)                                              \
        acc[(MH) * 4 + m][nf] = MFMA16(av_[m], bv[nf], acc[(MH) * 4 + m][nf]);    \
    __builtin_amdgcn_s_setprio(0);                                                \
    __builtin_amdgcn_sched_barrier(0);                                            \
  }

__global__ __launch_bounds__(512, 1)
void gemm_kv256(const bf16* __restrict__ A, const bf16* __restrict__ Bw,
                bf16* __restrict__ kout, bf16* __restrict__ vout)
{
  extern __shared__ __align__(16) char smem[];
  const int tid = threadIdx.x;
  const int w = tid >> 6, l = tid & 63;
  const int wm = w >> 2, wn = w & 3;
  const int cl = l & 15, rh = l >> 4;
  const int id = blockIdx.x;
  const int vid = (id & 7) * 256 + (id >> 3);   // XCD-chunked bijective swizzle
  const int brow = (vid >> 3) * 256, bcol = (vid & 7) * 256;

  // staging: instr q covers frags g=q*8+w (rowfrag i=g>>1=q*4+(w>>1), kk=w&1).
  // lane l -> row cl of rowfrag, k-chunk rh.
  const bf16* srcA = A  + (size_t)(brow + (w >> 1) * 16 + cl) * 1024 + (w & 1) * 32 + rh * 8;
  const bf16* srcB = Bw + (size_t)(bcol + (w >> 1) * 16 + cl) * 1024 + (w & 1) * 32 + rh * 8;
  char* dstA = smem + w * 1024 + l * 16;
  char* dstB = smem + 32768 + w * 1024 + l * 16;

#define KV_STAGE(T)                                                     \
  {                                                                     \
    const int koff_ = (T) * 64;                                         \
    char* dA_ = dstA + ((T) & 1) * 65536;                               \
    char* dB_ = dstB + ((T) & 1) * 65536;                               \
    _Pragma("unroll")                                                   \
    for (int q = 0; q < 4; ++q) {                                       \
      GL16(srcA + q * 65536 + koff_, dA_ + q * 8192);                   \
      GL16(srcB + q * 65536 + koff_, dB_ + q * 8192);                   \
    }                                                                   \
  }

  f32x4 acc[8][4] = {};

  KV_STAGE(0)
  KV_STAGE(1)
  asm volatile("s_waitcnt vmcnt(8)" ::: "memory");
  __builtin_amdgcn_sched_barrier(0);
  __builtin_amdgcn_s_barrier();

#pragma unroll 2
  for (int t = 0; t < 16; ++t) {
    const char* sb = smem + (t & 1) * 65536;
    bf16x8 bv[4];
    KV_PHASE(sb, 0, 0, 1)
    KV_PHASE(sb, 0, 1, 0)
    KV_PHASE(sb, 1, 0, 1)
    KV_PHASE(sb, 1, 1, 0)
    if (t < 15) {
      __builtin_amdgcn_s_barrier();          // all waves done reading slot t
      if (t < 14) {
        KV_STAGE(t + 2)                      // overwrite slot t (safe: post-barrier)
        asm volatile("s_waitcnt vmcnt(8)" ::: "memory");   // tile t+1 landed
      } else {
        asm volatile("s_waitcnt vmcnt(0)" ::: "memory");   // drain tile 15
      }
      __builtin_amdgcn_sched_barrier(0);
      __builtin_amdgcn_s_barrier();          // all waves see tile t+1
    }
  }
#undef KV_STAGE

  // epilogue: D row=(lane>>4)*4+reg, col=lane&15
#pragma unroll
  for (int mf = 0; mf < 8; ++mf) {
    int row0 = brow + wm * 128 + mf * 16 + rh * 4;
#pragma unroll
    for (int nf = 0; nf < 4; ++nf) {
      int colg = bcol + wn * 64 + nf * 16 + cl;
      bf16* __restrict__ C = (colg < 1024) ? kout : vout;
      int col = colg & 1023;
#pragma unroll
      for (int r = 0; r < 4; ++r)
        C[(size_t)(row0 + r) * 1024 + col] = (bf16)acc[mf][nf][r];
    }
  }
}

// ---------------- generic 64x64 GEMM (z selects problem): C[M,N] = A[M,K] @ B[N,K]^T ----------------
template<int OUT_F32>
__global__ __launch_bounds__(256, 4)
void gemm_bt64(const bf16* __restrict__ A0, const bf16* __restrict__ B0, void* __restrict__ C0,
               const bf16* __restrict__ A1, const bf16* __restrict__ B1, void* __restrict__ C1,
               int N, int K)
{
  const bf16* A = blockIdx.z ? A1 : A0;
  const bf16* B = blockIdx.z ? B1 : B0;
  void* C = blockIdx.z ? C1 : C0;
  __shared__ __align__(16) bf16 As[64 * 64];
  __shared__ __align__(16) bf16 Bs[64 * 64];
  const int tid = threadIdx.x, wave = tid >> 6, lane = tid & 63;
  const int wm = wave >> 1, wn = wave & 1;
  const int brow = blockIdx.y * 64, bcol = blockIdx.x * 64;
  const int r8 = lane >> 3, c8 = (lane & 7) * 8;
  const int cl = lane & 15, rh = lane >> 4;
  f32x4 acc[2][2] = {};

  for (int k0 = 0; k0 < K; k0 += 64) {
    __syncthreads();
    gload16(A + (size_t)(brow + wave * 16 + r8) * K + k0 + c8,     &As[(wave * 16) * 64]);
    gload16(A + (size_t)(brow + wave * 16 + 8 + r8) * K + k0 + c8, &As[(wave * 16 + 8) * 64]);
    gload16(B + (size_t)(bcol + wave * 16 + r8) * K + k0 + c8,     &Bs[(wave * 16) * 64]);
    gload16(B + (size_t)(bcol + wave * 16 + 8 + r8) * K + k0 + c8, &Bs[(wave * 16 + 8) * 64]);
    __syncthreads();
#pragma unroll
    for (int kk = 0; kk < 2; ++kk) {
      bf16x8 af[2], bfv[2];
#pragma unroll
      for (int m = 0; m < 2; ++m)
        af[m] = *(const bf16x8*)&As[(wm * 32 + m * 16 + cl) * 64 + kk * 32 + rh * 8];
#pragma unroll
      for (int n = 0; n < 2; ++n)
        bfv[n] = *(const bf16x8*)&Bs[(wn * 32 + n * 16 + cl) * 64 + kk * 32 + rh * 8];
#pragma unroll
      for (int m = 0; m < 2; ++m)
#pragma unroll
        for (int n = 0; n < 2; ++n)
          acc[m][n] = MFMA16(af[m], bfv[n], acc[m][n]);
    }
  }
#pragma unroll
  for (int m = 0; m < 2; ++m)
#pragma unroll
    for (int n = 0; n < 2; ++n) {
      int row0 = brow + wm * 32 + m * 16 + rh * 4;
      int col  = bcol + wn * 32 + n * 16 + cl;
#pragma unroll
      for (int r = 0; r < 4; ++r) {
        if (OUT_F32) ((float*)C)[(size_t)(row0 + r) * N + col] = acc[m][n][r];
        else         ((bf16*)C)[(size_t)(row0 + r) * N + col] = (bf16)acc[m][n][r];
      }
    }
}

// ---------------- SwiGLU-fused GEMM ----------------
__global__ __launch_bounds__(256, 4)
void gemm_swiglu(const bf16* __restrict__ A, const bf16* __restrict__ B12, bf16* __restrict__ G)
{
  __shared__ __align__(16) bf16 As[64 * 64];
  __shared__ __align__(16) bf16 B1s[64 * 64];
  __shared__ __align__(16) bf16 B2s[64 * 64];
  const int tid = threadIdx.x, wave = tid >> 6, lane = tid & 63;
  const int wm = wave >> 1, wn = wave & 1;
  const int brow = blockIdx.y * 64, bcol = blockIdx.x * 64;
  const int r8 = lane >> 3, c8 = (lane & 7) * 8;
  const int cl = lane & 15, rh = lane >> 4;
  f32x4 acc1[2][2] = {}, acc2[2][2] = {};

  for (int k0 = 0; k0 < 1024; k0 += 64) {
    __syncthreads();
    gload16(A   + (size_t)(brow + wave * 16 + r8) * 1024 + k0 + c8,            &As[(wave * 16) * 64]);
    gload16(A   + (size_t)(brow + wave * 16 + 8 + r8) * 1024 + k0 + c8,        &As[(wave * 16 + 8) * 64]);
    gload16(B12 + (size_t)(bcol + wave * 16 + r8) * 1024 + k0 + c8,            &B1s[(wave * 16) * 64]);
    gload16(B12 + (size_t)(bcol + wave * 16 + 8 + r8) * 1024 + k0 + c8,        &B1s[(wave * 16 + 8) * 64]);
    gload16(B12 + (size_t)(2048 + bcol + wave * 16 + r8) * 1024 + k0 + c8,     &B2s[(wave * 16) * 64]);
    gload16(B12 + (size_t)(2048 + bcol + wave * 16 + 8 + r8) * 1024 + k0 + c8, &B2s[(wave * 16 + 8) * 64]);
    __syncthreads();
#pragma unroll
    for (int kk = 0; kk < 2; ++kk) {
      bf16x8 af[2], b1v[2], b2v[2];
#pragma unroll
      for (int m = 0; m < 2; ++m)
        af[m] = *(const bf16x8*)&As[(wm * 32 + m * 16 + cl) * 64 + kk * 32 + rh * 8];
#pragma unroll
      for (int n = 0; n < 2; ++n) {
        b1v[n] = *(const bf16x8*)&B1s[(wn * 32 + n * 16 + cl) * 64 + kk * 32 + rh * 8];
        b2v[n] = *(const bf16x8*)&B2s[(wn * 32 + n * 16 + cl) * 64 + kk * 32 + rh * 8];
      }
#pragma unroll
      for (int m = 0; m < 2; ++m)
#pragma unroll
        for (int n = 0; n < 2; ++n) {
          acc1[m][n] = MFMA16(af[m], b1v[n], acc1[m][n]);
          acc2[m][n] = MFMA16(af[m], b2v[n], acc2[m][n]);
        }
    }
  }
#pragma unroll
  for (int m = 0; m < 2; ++m)
#pragma unroll
    for (int n = 0; n < 2; ++n) {
      int row0 = brow + wm * 32 + m * 16 + rh * 4;
      int col  = bcol + wn * 32 + n * 16 + cl;
#pragma unroll
      for (int r = 0; r < 4; ++r) {
        float h1 = acc1[m][n][r], h2 = acc2[m][n][r];
        G[(size_t)(row0 + r) * 2048 + col] = (bf16)(h1 / (1.f + __expf(-h1)) * h2);
      }
    }
}

// ---------------- fused attention: dots (MFMA) + slot-softmax + PV (VALU) ----------------
__global__ __launch_bounds__(256, 2)
void fused_attn(const bf16* __restrict__ s, const bf16* __restrict__ kq,
                const bf16* __restrict__ v, float* __restrict__ part,
                float* __restrict__ attn_sum)
{
  const int lc = blockIdx.x, b = blockIdx.y;
  const int tid = threadIdx.x, wave = tid >> 6, lane = tid & 63;
  const int cl = lane & 15, rh = lane >> 4;
  __shared__ __align__(16) bf16 ss[16 * 1024];
  __shared__ __align__(16) bf16 ks[128 * 64];
  __shared__ __align__(16) float p_lds[128 * 20];

  const bf16* sb = s + (size_t)b * 16 * 1024;
#pragma unroll
  for (int i = 0; i < 8; ++i)
    gload16(sb + i * 2048 + tid * 8, &ss[i * 2048 + wave * 512]);

  const bf16* kb = kq + ((size_t)b * 2048 + lc * 128) * 1024;
  f32x4 acc[2] = {};
  for (int kt = 0; kt < 16; ++kt) {
    __syncthreads();
#pragma unroll
    for (int i = 0; i < 4; ++i) {
      int row = i * 32 + wave * 8 + (lane >> 3);
      gload16(kb + (size_t)row * 1024 + kt * 64 + (lane & 7) * 8, &ks[(i * 32 + wave * 8) * 64]);
    }
    __syncthreads();
#pragma unroll
    for (int kk = 0; kk < 2; ++kk) {
      bf16x8 af = *(const bf16x8*)&ss[cl * 1024 + kt * 64 + kk * 32 + rh * 8];
#pragma unroll
      for (int n = 0; n < 2; ++n) {
        bf16x8 bfv = *(const bf16x8*)&ks[(wave * 32 + n * 16 + cl) * 64 + kk * 32 + rh * 8];
        acc[n] = MFMA16(af, bfv, acc[n]);
      }
    }
  }
  const float scale = 0.03125f;
  float rs[4] = {0.f, 0.f, 0.f, 0.f};
#pragma unroll
  for (int n = 0; n < 2; ++n) {
    float x[4];
#pragma unroll
    for (int r = 0; r < 4; ++r) x[r] = acc[n][r] * scale;
    float mx = fmaxf(fmaxf(x[0], x[1]), fmaxf(x[2], x[3]));
    mx = fmaxf(mx, __shfl_xor(mx, 16));
    mx = fmaxf(mx, __shfl_xor(mx, 32));
    float e[4], sm = 0.f;
#pragma unroll
    for (int r = 0; r < 4; ++r) { e[r] = __expf(x[r] - mx); sm += e[r]; }
    sm += __shfl_xor(sm, 16);
    sm += __shfl_xor(sm, 32);
    float inv = 1.f / sm;
    f32x4 pk;
#pragma unroll
    for (int r = 0; r < 4; ++r) { float av = e[r] * inv; rs[r] += av; pk[r] = av; }
    int ll = wave * 32 + n * 16 + cl;
    *(f32x4*)&p_lds[ll * 20 + rh * 4] = pk;
  }
#pragma unroll
  for (int off = 1; off < 16; off <<= 1) {
#pragma unroll
    for (int r = 0; r < 4; ++r) rs[r] += __shfl_xor(rs[r], off);
  }
  if (cl == 0) {
#pragma unroll
    for (int r = 0; r < 4; ++r) atomicAdd(&attn_sum[b * 16 + rh * 4 + r], rs[r]);
  }
  __syncthreads();

  const bf16* vb = v + ((size_t)b * 2048 + lc * 128) * 1024 + tid * 4;
  float pacc[16][4] = {};
  for (int l = 0; l < 128; ++l) {
    bf16x4 vv = *(const bf16x4*)(vb + (size_t)l * 1024);
    float vf0 = (float)vv[0], vf1 = (float)vv[1], vf2 = (float)vv[2], vf3 = (float)vv[3];
    float pv[16];
    *(f32x4*)&pv[0]  = *(const f32x4*)&p_lds[l * 20];
    *(f32x4*)&pv[4]  = *(const f32x4*)&p_lds[l * 20 + 4];
    *(f32x4*)&pv[8]  = *(const f32x4*)&p_lds[l * 20 + 8];
    *(f32x4*)&pv[12] = *(const f32x4*)&p_lds[l * 20 + 12];
#pragma unroll
    for (int n = 0; n < 16; ++n) {
      pacc[n][0] += pv[n] * vf0; pacc[n][1] += pv[n] * vf1;
      pacc[n][2] += pv[n] * vf2; pacc[n][3] += pv[n] * vf3;
    }
  }
  float* pb = part + ((size_t)(lc * 32 + b) * 16) * 1024 + tid * 4;
#pragma unroll
  for (int n = 0; n < 16; ++n)
    *(f32x4*)(pb + (size_t)n * 1024) = *(f32x4*)&pacc[n][0];
}

__global__ void updates_finalize(const float* __restrict__ part, const float* __restrict__ attn_sum,
                                 bf16* __restrict__ upd)
{
  int idx = blockIdx.x * 256 + threadIdx.x;
  int m = idx >> 10;
  float sm = 0.f;
#pragma unroll
  for (int ls = 0; ls < 16; ++ls) sm += part[idx + (size_t)ls * 524288];
  upd[idx] = (bf16)(sm / (attn_sum[m] + 1e-8f));
}

// ---------------- GRU pointwise + fused rmsnorm of new slots ----------------
__global__ __launch_bounds__(256)
void gru_pw_fused(const float* __restrict__ gi, const float* __restrict__ gh,
                  const float* __restrict__ bih, const float* __restrict__ bhh,
                  const float* __restrict__ g_sl,
                  float* __restrict__ slots, bf16* __restrict__ slots_bf,
                  bf16* __restrict__ s_bf, float* __restrict__ outp)
{
  const int m = blockIdx.x, tid = threadIdx.x;
  const int d0 = tid * 4;
  const size_t base = (size_t)m * 3072 + d0;
  f32x4 gir = *(const f32x4*)(gi + base),        ghr = *(const f32x4*)(gh + base);
  f32x4 giz = *(const f32x4*)(gi + base + 1024), ghz = *(const f32x4*)(gh + base + 1024);
  f32x4 gin = *(const f32x4*)(gi + base + 2048), ghn = *(const f32x4*)(gh + base + 2048);
  f32x4 br  = *(const f32x4*)(bih + d0),        bhr = *(const f32x4*)(bhh + d0);
  f32x4 bz  = *(const f32x4*)(bih + 1024 + d0), bhz = *(const f32x4*)(bhh + 1024 + d0);
  f32x4 bn  = *(const f32x4*)(bih + 2048 + d0), bhn = *(const f32x4*)(bhh + 2048 + d0);
  f32x4 h   = *(const f32x4*)(slots + (size_t)m * 1024 + d0);
  float o[4]; float ssum = 0.f;
#pragma unroll
  for (int j = 0; j < 4; ++j) {
    float r  = gir[j] + br[j] + ghr[j] + bhr[j];
    float z  = giz[j] + bz[j] + ghz[j] + bhz[j];
    float nn = gin[j] + bn[j];
    float hn = ghn[j] + bhn[j];
    r = 1.f / (1.f + expf(-r));
    z = 1.f / (1.f + expf(-z));
    nn = tanhf(nn + r * hn);
    o[j] = (1.f - z) * nn + z * h[j];
    ssum += o[j] * o[j];
  }
#pragma unroll
  for (int off = 32; off; off >>= 1) ssum += __shfl_xor(ssum, off);
  __shared__ float red[4];
  if ((tid & 63) == 0) red[tid >> 6] = ssum;
  __syncthreads();
  float tot = red[0] + red[1] + red[2] + red[3];
  float rsc = rsqrtf(tot * (1.f / 1024.f) + 1e-6f);
  f32x4 gv = *(const f32x4*)(g_sl + d0);
  f32x4 of; bf16x4 ob, sb;
#pragma unroll
  for (int j = 0; j < 4; ++j) { of[j] = o[j]; ob[j] = (bf16)o[j]; sb[j] = (bf16)(o[j] * rsc * gv[j]); }
  *(f32x4*)(slots + (size_t)m * 1024 + d0) = of;
  *(f32x4*)(outp  + (size_t)m * 1024 + d0) = of;
  *(bf16x4*)(slots_bf + (size_t)m * 1024 + d0) = ob;
  *(bf16x4*)(s_bf     + (size_t)m * 1024 + d0) = sb;
}

__global__ __launch_bounds__(256)
void init_slots_fused(const float* __restrict__ noise, const float* __restrict__ mu,
                      const float* __restrict__ sigma, const float* __restrict__ g_sl,
                      float* __restrict__ slots, bf16* __restrict__ slots_bf,
                      bf16* __restrict__ s_bf)
{
  const int m = blockIdx.x, tid = threadIdx.x;
  const int d0 = tid * 4;
  f32x4 nz = *(const f32x4*)(noise + (size_t)m * 1024 + d0);
  f32x4 mv = *(const f32x4*)(mu + d0);
  f32x4 sg = *(const f32x4*)(sigma + d0);
  float o[4]; float ssum = 0.f;
#pragma unroll
  for (int j = 0; j < 4; ++j) { o[j] = mv[j] + sg[j] * nz[j]; ssum += o[j] * o[j]; }
#pragma unroll
  for (int off = 32; off; off >>= 1) ssum += __shfl_xor(ssum, off);
  __shared__ float red[4];
  if ((tid & 63) == 0) red[tid >> 6] = ssum;
  __syncthreads();
  float tot = red[0] + red[1] + red[2] + red[3];
  float rsc = rsqrtf(tot * (1.f / 1024.f) + 1e-6f);
  f32x4 gv = *(const f32x4*)(g_sl + d0);
  f32x4 of; bf16x4 ob, sb;
#pragma unroll
  for (int j = 0; j < 4; ++j) { of[j] = o[j]; ob[j] = (bf16)o[j]; sb[j] = (bf16)(o[j] * rsc * gv[j]); }
  *(f32x4*)(slots + (size_t)m * 1024 + d0) = of;
  *(bf16x4*)(slots_bf + (size_t)m * 1024 + d0) = ob;
  *(bf16x4*)(s_bf     + (size_t)m * 1024 + d0) = sb;
}

__global__ __launch_bounds__(256)
void rmsnorm_cast(const float* __restrict__ x, const float* __restrict__ g, bf16* __restrict__ y)
{
  const int row = blockIdx.x, tid = threadIdx.x;
  float4 xv = ((const float4*)(x + (size_t)row * 1024))[tid];
  float ss = xv.x * xv.x + xv.y * xv.y + xv.z * xv.z + xv.w * xv.w;
#pragma unroll
  for (int off = 32; off; off >>= 1) ss += __shfl_xor(ss, off);
  __shared__ float red[4];
  if ((tid & 63) == 0) red[tid >> 6] = ss;
  __syncthreads();
  float tot = red[0] + red[1] + red[2] + red[3];
  float rs = rsqrtf(tot * (1.f / 1024.f) + 1e-6f);
  float4 gv = ((const float4*)g)[tid];
  bf16x4 o;
  o[0] = (bf16)(xv.x * rs * gv.x); o[1] = (bf16)(xv.y * rs * gv.y);
  o[2] = (bf16)(xv.z * rs * gv.z); o[3] = (bf16)(xv.w * rs * gv.w);
  *(bf16x4*)(y + (size_t)row * 1024 + tid * 4) = o;
}

// ---------------- transpose f32 -> bf16 (1024x1024) ----------------
__global__ __launch_bounds__(256)
void transpose_cast(const float* __restrict__ in, bf16* __restrict__ out)
{
  __shared__ float tile[32][33];
  const int bx = blockIdx.x * 32, by = blockIdx.y * 32;
  const int tx = threadIdx.x & 31, ty = threadIdx.x >> 5;
#pragma unroll
  for (int i = 0; i < 32; i += 8)
    tile[ty + i][tx] = in[(size_t)(by + ty + i) * 1024 + bx + tx];
  __syncthreads();
#pragma unroll
  for (int i = 0; i < 32; i += 8)
    out[(size_t)(bx + ty + i) * 1024 + by + tx] = (bf16)tile[tx][ty + i];
}

__global__ void cast_bf16_x4(const float* __restrict__ x, bf16* __restrict__ y)
{
  int i = (blockIdx.x * 256 + threadIdx.x) * 4;
  float4 v = *(const float4*)(x + i);
  bf16x4 o; o[0] = (bf16)v.x; o[1] = (bf16)v.y; o[2] = (bf16)v.z; o[3] = (bf16)v.w;
  *(bf16x4*)(y + i) = o;
}

// ---------------- host ----------------
extern "C" void kernel_launch(void* const* d_in, const int* in_sizes, int n_in,
                              void* d_out, int out_size, void* d_ws, size_t ws_size,
                              hipStream_t stream)
{
  const float* enc    = (const float*)d_in[0];
  const float* noise  = (const float*)d_in[1];
  const float* mu     = (const float*)d_in[2];
  const float* sigma  = (const float*)d_in[3];
  const float* g_in   = (const float*)d_in[4];
  const float* g_sl   = (const float*)d_in[5];
  const float* Wq     = (const float*)d_in[6];
  const float* Wk     = (const float*)d_in[7];
  const float* Wv     = (const float*)d_in[8];
  const float* w1     = (const float*)d_in[9];
  const float* w2     = (const float*)d_in[10];
  const float* w3     = (const float*)d_in[11];
  const float* Wih    = (const float*)d_in[12];
  const float* Whh    = (const float*)d_in[13];
  const float* bih    = (const float*)d_in[14];
  const float* bhh    = (const float*)d_in[15];

  char* p = (char*)d_ws;
  auto alloc = [&](size_t bytes) { char* r = p; p += (bytes + 255) & ~(size_t)255; return (void*)r; };

  bf16* inputs  = (bf16*)alloc((size_t)32 * 2048 * 1024 * 2);
  bf16* kqbuf   = (bf16*)alloc((size_t)32 * 2048 * 1024 * 2);
  bf16* vbuf    = (bf16*)alloc((size_t)32 * 2048 * 1024 * 2);
  bf16* wkv_b   = (bf16*)alloc((size_t)2048 * 1024 * 2);       // [M; Wv]
  bf16* wqT_b   = (bf16*)alloc((size_t)1024 * 1024 * 2);
  bf16* wkT_b   = (bf16*)alloc((size_t)1024 * 1024 * 2);
  bf16* w12_b   = (bf16*)alloc((size_t)4096 * 1024 * 2);       // [w1; w2]
  bf16* w3_b    = (bf16*)alloc((size_t)1024 * 2048 * 2);
  bf16* wih_b   = (bf16*)alloc((size_t)3072 * 1024 * 2);
  bf16* whh_b   = (bf16*)alloc((size_t)3072 * 1024 * 2);
  float* slots  = (float*)alloc(512 * 1024 * 4);
  bf16* slots_bf= (bf16*)alloc(512 * 1024 * 2);
  bf16* s_bf    = (bf16*)alloc(512 * 1024 * 2);
  float* attn_sum = (float*)alloc(32 * 16 * 4);
  float* part   = (float*)alloc((size_t)16 * 512 * 1024 * 4);
  bf16* upd_bf  = (bf16*)alloc(512 * 1024 * 2);
  bf16* g_bf    = (bf16*)alloc((size_t)512 * 2048 * 2);
  bf16* swout   = (bf16*)alloc(512 * 1024 * 2);
  float* gif    = (float*)alloc((size_t)512 * 3072 * 4);
  float* ghf    = (float*)alloc((size_t)512 * 3072 * 4);

  // ---- precompute: M = Wq^T @ Wk ----
  transpose_cast<<<dim3(32, 32), 256, 0, stream>>>(Wq, wqT_b);
  transpose_cast<<<dim3(32, 32), 256, 0, stream>>>(Wk, wkT_b);
  gemm_bt64<0><<<dim3(16, 16, 1), 256, 0, stream>>>(wqT_b, wkT_b, wkv_b, wqT_b, wkT_b, wkv_b, 1024, 1024);
  cast_bf16_x4<<<1024, 256, 0, stream>>>(Wv, wkv_b + (size_t)1024 * 1024);
  cast_bf16_x4<<<2048, 256, 0, stream>>>(w1, w12_b);
  cast_bf16_x4<<<2048, 256, 0, stream>>>(w2, w12_b + (size_t)2048 * 1024);
  cast_bf16_x4<<<2048, 256, 0, stream>>>(w3, w3_b);
  cast_bf16_x4<<<3072, 256, 0, stream>>>(Wih, wih_b);
  cast_bf16_x4<<<3072, 256, 0, stream>>>(Whh, whh_b);

  // ---- stage 1 ----
  rmsnorm_cast<<<65536, 256, 0, stream>>>(enc, g_in, inputs);
  init_slots_fused<<<512, 256, 0, stream>>>(noise, mu, sigma, g_sl, slots, slots_bf, s_bf);
  hipFuncSetAttribute(reinterpret_cast<const void*>(gemm_kv256),
                      hipFuncAttributeMaxDynamicSharedMemorySize, 131072);
  gemm_kv256<<<2048, 512, 131072, stream>>>(inputs, wkv_b, kqbuf, vbuf);

  // ---- iterations ----
  for (int it = 0; it < 4; ++it) {
    hipMemsetAsync(attn_sum, 0, 32 * 16 * 4, stream);
    fused_attn<<<dim3(16, 32), 256, 0, stream>>>(s_bf, kqbuf, vbuf, part, attn_sum);
    updates_finalize<<<2048, 256, 0, stream>>>(part, attn_sum, upd_bf);
    gemm_swiglu<<<dim3(32, 8), 256, 0, stream>>>(upd_bf, w12_b, g_bf);
    gemm_bt64<0><<<dim3(16, 8, 1), 256, 0, stream>>>(g_bf, w3_b, swout, g_bf, w3_b, swout, 1024, 2048);
    gemm_bt64<1><<<dim3(48, 8, 2), 256, 0, stream>>>(swout, wih_b, gif, slots_bf, whh_b, ghf, 3072, 1024);
    float* outp = (it == 3) ? (float*)d_out : slots;
    gru_pw_fused<<<512, 256, 0, stream>>>(gif, ghf, bih, bhh, g_sl, slots, slots_bf, s_bf, outp);
  }
}

// Round 6
// 784.154 us; speedup vs baseline: 1.4493x; 1.4493x over previous
//
#include <hip/hip_runtime.h>
#include <hip/hip_bf16.h>
#include <stdint.h>

// SlotAttention MI355X. Round 6: algebraic elimination of BOTH big projections.
//   dots = (s@M')@inputs^T  (qm = s@M' is 512-row tiny GEMM per iter)
//   updates = [(attn+eps)@inputs / sum] @ Wv^T  (Wv applied post-contraction)
// Stage 1 = encoder rmsnorm only. No 65536-row GEMM anywhere.
// B=32 L=2048 D=1024 N=16 ITERS=4 H=2048.

typedef __bf16 bf16;
typedef __bf16 bf16x2 __attribute__((ext_vector_type(2)));
typedef __bf16 bf16x4 __attribute__((ext_vector_type(4)));
typedef __bf16 bf16x8 __attribute__((ext_vector_type(8)));
typedef float  f32x4  __attribute__((ext_vector_type(4)));

#define MFMA16(a,b,c) __builtin_amdgcn_mfma_f32_16x16x32_bf16((a),(b),(c),0,0,0)

__device__ __forceinline__ void gload16(const void* g, void* l) {
  __builtin_amdgcn_global_load_lds((__attribute__((address_space(1))) const void*)g,
                                   (__attribute__((address_space(3))) void*)l, 16, 0, 0);
}

// ---------------- generic 64x64 GEMM (z selects problem): C[M,N] = A[M,K] @ B[N,K]^T ----------------
template<int OUT_F32>
__global__ __launch_bounds__(256, 4)
void gemm_bt64(const bf16* __restrict__ A0, const bf16* __restrict__ B0, void* __restrict__ C0,
               const bf16* __restrict__ A1, const bf16* __restrict__ B1, void* __restrict__ C1,
               int N, int K)
{
  const bf16* A = blockIdx.z ? A1 : A0;
  const bf16* B = blockIdx.z ? B1 : B0;
  void* C = blockIdx.z ? C1 : C0;
  __shared__ __align__(16) bf16 As[64 * 64];
  __shared__ __align__(16) bf16 Bs[64 * 64];
  const int tid = threadIdx.x, wave = tid >> 6, lane = tid & 63;
  const int wm = wave >> 1, wn = wave & 1;
  const int brow = blockIdx.y * 64, bcol = blockIdx.x * 64;
  const int r8 = lane >> 3, c8 = (lane & 7) * 8;
  const int cl = lane & 15, rh = lane >> 4;
  f32x4 acc[2][2] = {};

  for (int k0 = 0; k0 < K; k0 += 64) {
    __syncthreads();
    gload16(A + (size_t)(brow + wave * 16 + r8) * K + k0 + c8,     &As[(wave * 16) * 64]);
    gload16(A + (size_t)(brow + wave * 16 + 8 + r8) * K + k0 + c8, &As[(wave * 16 + 8) * 64]);
    gload16(B + (size_t)(bcol + wave * 16 + r8) * K + k0 + c8,     &Bs[(wave * 16) * 64]);
    gload16(B + (size_t)(bcol + wave * 16 + 8 + r8) * K + k0 + c8, &Bs[(wave * 16 + 8) * 64]);
    __syncthreads();
#pragma unroll
    for (int kk = 0; kk < 2; ++kk) {
      bf16x8 af[2], bfv[2];
#pragma unroll
      for (int m = 0; m < 2; ++m)
        af[m] = *(const bf16x8*)&As[(wm * 32 + m * 16 + cl) * 64 + kk * 32 + rh * 8];
#pragma unroll
      for (int n = 0; n < 2; ++n)
        bfv[n] = *(const bf16x8*)&Bs[(wn * 32 + n * 16 + cl) * 64 + kk * 32 + rh * 8];
#pragma unroll
      for (int m = 0; m < 2; ++m)
#pragma unroll
        for (int n = 0; n < 2; ++n)
          acc[m][n] = MFMA16(af[m], bfv[n], acc[m][n]);
    }
  }
#pragma unroll
  for (int m = 0; m < 2; ++m)
#pragma unroll
    for (int n = 0; n < 2; ++n) {
      int row0 = brow + wm * 32 + m * 16 + rh * 4;
      int col  = bcol + wn * 32 + n * 16 + cl;
#pragma unroll
      for (int r = 0; r < 4; ++r) {
        if (OUT_F32) ((float*)C)[(size_t)(row0 + r) * N + col] = acc[m][n][r];
        else         ((bf16*)C)[(size_t)(row0 + r) * N + col] = (bf16)acc[m][n][r];
      }
    }
}

// ---------------- SwiGLU-fused GEMM ----------------
__global__ __launch_bounds__(256, 4)
void gemm_swiglu(const bf16* __restrict__ A, const bf16* __restrict__ B12, bf16* __restrict__ G)
{
  __shared__ __align__(16) bf16 As[64 * 64];
  __shared__ __align__(16) bf16 B1s[64 * 64];
  __shared__ __align__(16) bf16 B2s[64 * 64];
  const int tid = threadIdx.x, wave = tid >> 6, lane = tid & 63;
  const int wm = wave >> 1, wn = wave & 1;
  const int brow = blockIdx.y * 64, bcol = blockIdx.x * 64;
  const int r8 = lane >> 3, c8 = (lane & 7) * 8;
  const int cl = lane & 15, rh = lane >> 4;
  f32x4 acc1[2][2] = {}, acc2[2][2] = {};

  for (int k0 = 0; k0 < 1024; k0 += 64) {
    __syncthreads();
    gload16(A   + (size_t)(brow + wave * 16 + r8) * 1024 + k0 + c8,            &As[(wave * 16) * 64]);
    gload16(A   + (size_t)(brow + wave * 16 + 8 + r8) * 1024 + k0 + c8,        &As[(wave * 16 + 8) * 64]);
    gload16(B12 + (size_t)(bcol + wave * 16 + r8) * 1024 + k0 + c8,            &B1s[(wave * 16) * 64]);
    gload16(B12 + (size_t)(bcol + wave * 16 + 8 + r8) * 1024 + k0 + c8,        &B1s[(wave * 16 + 8) * 64]);
    gload16(B12 + (size_t)(2048 + bcol + wave * 16 + r8) * 1024 + k0 + c8,     &B2s[(wave * 16) * 64]);
    gload16(B12 + (size_t)(2048 + bcol + wave * 16 + 8 + r8) * 1024 + k0 + c8, &B2s[(wave * 16 + 8) * 64]);
    __syncthreads();
#pragma unroll
    for (int kk = 0; kk < 2; ++kk) {
      bf16x8 af[2], b1v[2], b2v[2];
#pragma unroll
      for (int m = 0; m < 2; ++m)
        af[m] = *(const bf16x8*)&As[(wm * 32 + m * 16 + cl) * 64 + kk * 32 + rh * 8];
#pragma unroll
      for (int n = 0; n < 2; ++n) {
        b1v[n] = *(const bf16x8*)&B1s[(wn * 32 + n * 16 + cl) * 64 + kk * 32 + rh * 8];
        b2v[n] = *(const bf16x8*)&B2s[(wn * 32 + n * 16 + cl) * 64 + kk * 32 + rh * 8];
      }
#pragma unroll
      for (int m = 0; m < 2; ++m)
#pragma unroll
        for (int n = 0; n < 2; ++n) {
          acc1[m][n] = MFMA16(af[m], b1v[n], acc1[m][n]);
          acc2[m][n] = MFMA16(af[m], b2v[n], acc2[m][n]);
        }
    }
  }
#pragma unroll
  for (int m = 0; m < 2; ++m)
#pragma unroll
    for (int n = 0; n < 2; ++n) {
      int row0 = brow + wm * 32 + m * 16 + rh * 4;
      int col  = bcol + wn * 32 + n * 16 + cl;
#pragma unroll
      for (int r = 0; r < 4; ++r) {
        float h1 = acc1[m][n][r], h2 = acc2[m][n][r];
        G[(size_t)(row0 + r) * 2048 + col] = (bf16)(h1 / (1.f + __expf(-h1)) * h2);
      }
    }
}

// ---------------- fused attention: dots (MFMA) + slot-softmax + P@inputs (VALU) ----------------
// qm [B*16, 1024] bf16; x = inputs [B, 2048, 1024] bf16 serves as both K and V.
__global__ __launch_bounds__(256, 2)
void fused_attn(const bf16* __restrict__ qm, const bf16* __restrict__ x,
                float* __restrict__ part, float* __restrict__ attn_sum)
{
  const int lc = blockIdx.x, b = blockIdx.y;
  const int tid = threadIdx.x, wave = tid >> 6, lane = tid & 63;
  const int cl = lane & 15, rh = lane >> 4;
  __shared__ __align__(16) bf16 ss[16 * 1024];
  __shared__ __align__(16) bf16 ks[128 * 64];
  __shared__ __align__(16) float p_lds[128 * 20];

  const bf16* sb = qm + (size_t)b * 16 * 1024;
#pragma unroll
  for (int i = 0; i < 8; ++i)
    gload16(sb + i * 2048 + tid * 8, &ss[i * 2048 + wave * 512]);

  const bf16* kb = x + ((size_t)b * 2048 + lc * 128) * 1024;
  f32x4 acc[2] = {};
  for (int kt = 0; kt < 16; ++kt) {
    __syncthreads();
#pragma unroll
    for (int i = 0; i < 4; ++i) {
      int row = i * 32 + wave * 8 + (lane >> 3);
      gload16(kb + (size_t)row * 1024 + kt * 64 + (lane & 7) * 8, &ks[(i * 32 + wave * 8) * 64]);
    }
    __syncthreads();
#pragma unroll
    for (int kk = 0; kk < 2; ++kk) {
      bf16x8 af = *(const bf16x8*)&ss[cl * 1024 + kt * 64 + kk * 32 + rh * 8];
#pragma unroll
      for (int n = 0; n < 2; ++n) {
        bf16x8 bfv = *(const bf16x8*)&ks[(wave * 32 + n * 16 + cl) * 64 + kk * 32 + rh * 8];
        acc[n] = MFMA16(af, bfv, acc[n]);
      }
    }
  }
  const float scale = 0.03125f;   // 1024^-0.5
  float rs[4] = {0.f, 0.f, 0.f, 0.f};
#pragma unroll
  for (int n = 0; n < 2; ++n) {
    float xv[4];
#pragma unroll
    for (int r = 0; r < 4; ++r) xv[r] = acc[n][r] * scale;
    float mx = fmaxf(fmaxf(xv[0], xv[1]), fmaxf(xv[2], xv[3]));
    mx = fmaxf(mx, __shfl_xor(mx, 16));
    mx = fmaxf(mx, __shfl_xor(mx, 32));
    float e[4], sm = 0.f;
#pragma unroll
    for (int r = 0; r < 4; ++r) { e[r] = __expf(xv[r] - mx); sm += e[r]; }
    sm += __shfl_xor(sm, 16);
    sm += __shfl_xor(sm, 32);
    float inv = 1.f / sm;
    f32x4 pk;
#pragma unroll
    for (int r = 0; r < 4; ++r) { float av = e[r] * inv; rs[r] += av; pk[r] = av; }
    int ll = wave * 32 + n * 16 + cl;
    *(f32x4*)&p_lds[ll * 20 + rh * 4] = pk;
  }
#pragma unroll
  for (int off = 1; off < 16; off <<= 1) {
#pragma unroll
    for (int r = 0; r < 4; ++r) rs[r] += __shfl_xor(rs[r], off);
  }
  if (cl == 0) {
#pragma unroll
    for (int r = 0; r < 4; ++r) atomicAdd(&attn_sum[b * 16 + rh * 4 + r], rs[r]);
  }
  __syncthreads();

  // P @ x : thread owns 4 d-columns; stream x chunk (L2-hot from dots pass).
  const bf16* vb = x + ((size_t)b * 2048 + lc * 128) * 1024 + tid * 4;
  float pacc[16][4] = {};
  for (int l = 0; l < 128; ++l) {
    bf16x4 vv = *(const bf16x4*)(vb + (size_t)l * 1024);
    float vf0 = (float)vv[0], vf1 = (float)vv[1], vf2 = (float)vv[2], vf3 = (float)vv[3];
    float pv[16];
    *(f32x4*)&pv[0]  = *(const f32x4*)&p_lds[l * 20];
    *(f32x4*)&pv[4]  = *(const f32x4*)&p_lds[l * 20 + 4];
    *(f32x4*)&pv[8]  = *(const f32x4*)&p_lds[l * 20 + 8];
    *(f32x4*)&pv[12] = *(const f32x4*)&p_lds[l * 20 + 12];
#pragma unroll
    for (int n = 0; n < 16; ++n) {
      pacc[n][0] += pv[n] * vf0; pacc[n][1] += pv[n] * vf1;
      pacc[n][2] += pv[n] * vf2; pacc[n][3] += pv[n] * vf3;
    }
  }
  float* pb = part + ((size_t)(lc * 32 + b) * 16) * 1024 + tid * 4;
#pragma unroll
  for (int n = 0; n < 16; ++n)
    *(f32x4*)(pb + (size_t)n * 1024) = *(f32x4*)&pacc[n][0];
}

// sum 16 l-splits, normalize by attn_sum -> updraw (bf16), pre-Wv
__global__ void updates_finalize(const float* __restrict__ part, const float* __restrict__ attn_sum,
                                 bf16* __restrict__ updraw)
{
  int idx = blockIdx.x * 256 + threadIdx.x;
  int m = idx >> 10;
  float sm = 0.f;
#pragma unroll
  for (int ls = 0; ls < 16; ++ls) sm += part[idx + (size_t)ls * 524288];
  updraw[idx] = (bf16)(sm / (attn_sum[m] + 1e-8f));
}

// ---------------- GRU pointwise + fused rmsnorm of new slots ----------------
__global__ __launch_bounds__(256)
void gru_pw_fused(const float* __restrict__ gi, const float* __restrict__ gh,
                  const float* __restrict__ bih, const float* __restrict__ bhh,
                  const float* __restrict__ g_sl,
                  float* __restrict__ slots, bf16* __restrict__ slots_bf,
                  bf16* __restrict__ s_bf, float* __restrict__ outp)
{
  const int m = blockIdx.x, tid = threadIdx.x;
  const int d0 = tid * 4;
  const size_t base = (size_t)m * 3072 + d0;
  f32x4 gir = *(const f32x4*)(gi + base),        ghr = *(const f32x4*)(gh + base);
  f32x4 giz = *(const f32x4*)(gi + base + 1024), ghz = *(const f32x4*)(gh + base + 1024);
  f32x4 gin = *(const f32x4*)(gi + base + 2048), ghn = *(const f32x4*)(gh + base + 2048);
  f32x4 br  = *(const f32x4*)(bih + d0),        bhr = *(const f32x4*)(bhh + d0);
  f32x4 bz  = *(const f32x4*)(bih + 1024 + d0), bhz = *(const f32x4*)(bhh + 1024 + d0);
  f32x4 bn  = *(const f32x4*)(bih + 2048 + d0), bhn = *(const f32x4*)(bhh + 2048 + d0);
  f32x4 h   = *(const f32x4*)(slots + (size_t)m * 1024 + d0);
  float o[4]; float ssum = 0.f;
#pragma unroll
  for (int j = 0; j < 4; ++j) {
    float r  = gir[j] + br[j] + ghr[j] + bhr[j];
    float z  = giz[j] + bz[j] + ghz[j] + bhz[j];
    float nn = gin[j] + bn[j];
    float hn = ghn[j] + bhn[j];
    r = 1.f / (1.f + expf(-r));
    z = 1.f / (1.f + expf(-z));
    nn = tanhf(nn + r * hn);
    o[j] = (1.f - z) * nn + z * h[j];
    ssum += o[j] * o[j];
  }
#pragma unroll
  for (int off = 32; off; off >>= 1) ssum += __shfl_xor(ssum, off);
  __shared__ float red[4];
  if ((tid & 63) == 0) red[tid >> 6] = ssum;
  __syncthreads();
  float tot = red[0] + red[1] + red[2] + red[3];
  float rsc = rsqrtf(tot * (1.f / 1024.f) + 1e-6f);
  f32x4 gv = *(const f32x4*)(g_sl + d0);
  f32x4 of; bf16x4 ob, sb;
#pragma unroll
  for (int j = 0; j < 4; ++j) { of[j] = o[j]; ob[j] = (bf16)o[j]; sb[j] = (bf16)(o[j] * rsc * gv[j]); }
  *(f32x4*)(slots + (size_t)m * 1024 + d0) = of;
  *(f32x4*)(outp  + (size_t)m * 1024 + d0) = of;
  *(bf16x4*)(slots_bf + (size_t)m * 1024 + d0) = ob;
  *(bf16x4*)(s_bf     + (size_t)m * 1024 + d0) = sb;
}

__global__ __launch_bounds__(256)
void init_slots_fused(const float* __restrict__ noise, const float* __restrict__ mu,
                      const float* __restrict__ sigma, const float* __restrict__ g_sl,
                      float* __restrict__ slots, bf16* __restrict__ slots_bf,
                      bf16* __restrict__ s_bf)
{
  const int m = blockIdx.x, tid = threadIdx.x;
  const int d0 = tid * 4;
  f32x4 nz = *(const f32x4*)(noise + (size_t)m * 1024 + d0);
  f32x4 mv = *(const f32x4*)(mu + d0);
  f32x4 sg = *(const f32x4*)(sigma + d0);
  float o[4]; float ssum = 0.f;
#pragma unroll
  for (int j = 0; j < 4; ++j) { o[j] = mv[j] + sg[j] * nz[j]; ssum += o[j] * o[j]; }
#pragma unroll
  for (int off = 32; off; off >>= 1) ssum += __shfl_xor(ssum, off);
  __shared__ float red[4];
  if ((tid & 63) == 0) red[tid >> 6] = ssum;
  __syncthreads();
  float tot = red[0] + red[1] + red[2] + red[3];
  float rsc = rsqrtf(tot * (1.f / 1024.f) + 1e-6f);
  f32x4 gv = *(const f32x4*)(g_sl + d0);
  f32x4 of; bf16x4 ob, sb;
#pragma unroll
  for (int j = 0; j < 4; ++j) { of[j] = o[j]; ob[j] = (bf16)o[j]; sb[j] = (bf16)(o[j] * rsc * gv[j]); }
  *(f32x4*)(slots + (size_t)m * 1024 + d0) = of;
  *(bf16x4*)(slots_bf + (size_t)m * 1024 + d0) = ob;
  *(bf16x4*)(s_bf     + (size_t)m * 1024 + d0) = sb;
}

__global__ __launch_bounds__(256)
void rmsnorm_cast(const float* __restrict__ x, const float* __restrict__ g, bf16* __restrict__ y)
{
  const int row = blockIdx.x, tid = threadIdx.x;
  float4 xv = ((const float4*)(x + (size_t)row * 1024))[tid];
  float ss = xv.x * xv.x + xv.y * xv.y + xv.z * xv.z + xv.w * xv.w;
#pragma unroll
  for (int off = 32; off; off >>= 1) ss += __shfl_xor(ss, off);
  __shared__ float red[4];
  if ((tid & 63) == 0) red[tid >> 6] = ss;
  __syncthreads();
  float tot = red[0] + red[1] + red[2] + red[3];
  float rs = rsqrtf(tot * (1.f / 1024.f) + 1e-6f);
  float4 gv = ((const float4*)g)[tid];
  bf16x4 o;
  o[0] = (bf16)(xv.x * rs * gv.x); o[1] = (bf16)(xv.y * rs * gv.y);
  o[2] = (bf16)(xv.z * rs * gv.z); o[3] = (bf16)(xv.w * rs * gv.w);
  *(bf16x4*)(y + (size_t)row * 1024 + tid * 4) = o;
}

// ---------------- transpose f32 -> bf16 (1024x1024) ----------------
__global__ __launch_bounds__(256)
void transpose_cast(const float* __restrict__ in, bf16* __restrict__ out)
{
  __shared__ float tile[32][33];
  const int bx = blockIdx.x * 32, by = blockIdx.y * 32;
  const int tx = threadIdx.x & 31, ty = threadIdx.x >> 5;
#pragma unroll
  for (int i = 0; i < 32; i += 8)
    tile[ty + i][tx] = in[(size_t)(by + ty + i) * 1024 + bx + tx];
  __syncthreads();
#pragma unroll
  for (int i = 0; i < 32; i += 8)
    out[(size_t)(bx + ty + i) * 1024 + by + tx] = (bf16)tile[tx][ty + i];
}

__global__ void cast_bf16_x4(const float* __restrict__ x, bf16* __restrict__ y)
{
  int i = (blockIdx.x * 256 + threadIdx.x) * 4;
  float4 v = *(const float4*)(x + i);
  bf16x4 o; o[0] = (bf16)v.x; o[1] = (bf16)v.y; o[2] = (bf16)v.z; o[3] = (bf16)v.w;
  *(bf16x4*)(y + i) = o;
}

// ---------------- host ----------------
extern "C" void kernel_launch(void* const* d_in, const int* in_sizes, int n_in,
                              void* d_out, int out_size, void* d_ws, size_t ws_size,
                              hipStream_t stream)
{
  const float* enc    = (const float*)d_in[0];
  const float* noise  = (const float*)d_in[1];
  const float* mu     = (const float*)d_in[2];
  const float* sigma  = (const float*)d_in[3];
  const float* g_in   = (const float*)d_in[4];
  const float* g_sl   = (const float*)d_in[5];
  const float* Wq     = (const float*)d_in[6];
  const float* Wk     = (const float*)d_in[7];
  const float* Wv     = (const float*)d_in[8];
  const float* w1     = (const float*)d_in[9];
  const float* w2     = (const float*)d_in[10];
  const float* w3     = (const float*)d_in[11];
  const float* Wih    = (const float*)d_in[12];
  const float* Whh    = (const float*)d_in[13];
  const float* bih    = (const float*)d_in[14];
  const float* bhh    = (const float*)d_in[15];

  char* p = (char*)d_ws;
  auto alloc = [&](size_t bytes) { char* r = p; p += (bytes + 255) & ~(size_t)255; return (void*)r; };

  bf16* inputs  = (bf16*)alloc((size_t)32 * 2048 * 1024 * 2);  // 128MB, serves as K & V
  bf16* qm_w    = (bf16*)alloc((size_t)1024 * 1024 * 2);       // M'^T = Wk^T @ Wq
  bf16* wv_b    = (bf16*)alloc((size_t)1024 * 1024 * 2);
  bf16* wqT_b   = (bf16*)alloc((size_t)1024 * 1024 * 2);
  bf16* wkT_b   = (bf16*)alloc((size_t)1024 * 1024 * 2);
  bf16* w12_b   = (bf16*)alloc((size_t)4096 * 1024 * 2);       // [w1; w2]
  bf16* w3_b    = (bf16*)alloc((size_t)1024 * 2048 * 2);
  bf16* wih_b   = (bf16*)alloc((size_t)3072 * 1024 * 2);
  bf16* whh_b   = (bf16*)alloc((size_t)3072 * 1024 * 2);
  float* slots  = (float*)alloc(512 * 1024 * 4);
  bf16* slots_bf= (bf16*)alloc(512 * 1024 * 2);
  bf16* s_bf    = (bf16*)alloc(512 * 1024 * 2);
  bf16* qm_bf   = (bf16*)alloc(512 * 1024 * 2);
  float* attn_sum = (float*)alloc(32 * 16 * 4);
  float* part   = (float*)alloc((size_t)16 * 512 * 1024 * 4);  // 32MB
  bf16* updraw  = (bf16*)alloc(512 * 1024 * 2);
  bf16* upd_bf  = (bf16*)alloc(512 * 1024 * 2);
  bf16* g_bf    = (bf16*)alloc((size_t)512 * 2048 * 2);
  bf16* swout   = (bf16*)alloc(512 * 1024 * 2);
  float* gif    = (float*)alloc((size_t)512 * 3072 * 4);
  float* ghf    = (float*)alloc((size_t)512 * 3072 * 4);

  // ---- precompute: qm_w = (Wq^T Wk)^T = Wk^T @ Wq ; plain Wv cast ----
  transpose_cast<<<dim3(32, 32), 256, 0, stream>>>(Wq, wqT_b);
  transpose_cast<<<dim3(32, 32), 256, 0, stream>>>(Wk, wkT_b);
  gemm_bt64<0><<<dim3(16, 16, 1), 256, 0, stream>>>(wkT_b, wqT_b, qm_w, wkT_b, wqT_b, qm_w, 1024, 1024);
  cast_bf16_x4<<<1024, 256, 0, stream>>>(Wv, wv_b);
  cast_bf16_x4<<<2048, 256, 0, stream>>>(w1, w12_b);
  cast_bf16_x4<<<2048, 256, 0, stream>>>(w2, w12_b + (size_t)2048 * 1024);
  cast_bf16_x4<<<2048, 256, 0, stream>>>(w3, w3_b);
  cast_bf16_x4<<<3072, 256, 0, stream>>>(Wih, wih_b);
  cast_bf16_x4<<<3072, 256, 0, stream>>>(Whh, whh_b);

  // ---- stage 1: just the encoder rmsnorm ----
  rmsnorm_cast<<<65536, 256, 0, stream>>>(enc, g_in, inputs);
  init_slots_fused<<<512, 256, 0, stream>>>(noise, mu, sigma, g_sl, slots, slots_bf, s_bf);

  // ---- iterations ----
  for (int it = 0; it < 4; ++it) {
    // qm = s_norm @ M'  (tiny GEMM, replaces the 65536-row K projection)
    gemm_bt64<0><<<dim3(16, 8, 1), 256, 0, stream>>>(s_bf, qm_w, qm_bf, s_bf, qm_w, qm_bf, 1024, 1024);
    hipMemsetAsync(attn_sum, 0, 32 * 16 * 4, stream);
    fused_attn<<<dim3(16, 32), 256, 0, stream>>>(qm_bf, inputs, part, attn_sum);
    updates_finalize<<<2048, 256, 0, stream>>>(part, attn_sum, updraw);
    // upd = updraw @ Wv^T  (tiny GEMM, replaces the 65536-row V projection)
    gemm_bt64<0><<<dim3(16, 8, 1), 256, 0, stream>>>(updraw, wv_b, upd_bf, updraw, wv_b, upd_bf, 1024, 1024);
    gemm_swiglu<<<dim3(32, 8), 256, 0, stream>>>(upd_bf, w12_b, g_bf);
    gemm_bt64<0><<<dim3(16, 8, 1), 256, 0, stream>>>(g_bf, w3_b, swout, g_bf, w3_b, swout, 1024, 2048);
    gemm_bt64<1><<<dim3(48, 8, 2), 256, 0, stream>>>(swout, wih_b, gif, slots_bf, whh_b, ghf, 3072, 1024);
    float* outp = (it == 3) ? (float*)d_out : slots;
    gru_pw_fused<<<512, 256, 0, stream>>>(gif, ghf, bih, bhh, g_sl, slots, slots_bf, s_bf, outp);
  }
}